// Round 12
// baseline (561.122 us; speedup 1.0000x reference)
//
#include <hip/hip_runtime.h>

#define HID 128
#define NH 8

typedef __attribute__((ext_vector_type(8))) short short8;
typedef __attribute__((ext_vector_type(4))) float f32x4;
typedef __attribute__((ext_vector_type(2))) float f32x2;

__device__ __forceinline__ unsigned short f2bf(float f) {
    unsigned int u = __float_as_uint(f);
    u = (u + 0x7FFF + ((u >> 16) & 1)) >> 16;
    return (unsigned short)u;
}
__device__ __forceinline__ float bf2f(unsigned short s) {
    return __uint_as_float((unsigned int)s << 16);
}
__device__ __forceinline__ unsigned int pack2bf(float lo, float hi) {
    return (unsigned int)f2bf(lo) | ((unsigned int)f2bf(hi) << 16);
}

// ---------------- fused: weight conversion (blocks 0..63) + histogram ----------------
__global__ void k_init(const float* __restrict__ qw, const float* __restrict__ kw,
                       const float* __restrict__ vw, const float* __restrict__ ow,
                       unsigned short* __restrict__ wbf,
                       const int* __restrict__ row, int E, int* __restrict__ count) {
    int bid = blockIdx.x;
    int t = threadIdx.x;
    if (bid < 64) {
        int i = bid * 256 + t;
        int idx = i * 4;
        int m = idx >> 14;
        int off = idx & 16383;
        const float* src = (m == 0) ? qw : (m == 1) ? kw : (m == 2) ? vw : ow;
        float4 v = *(const float4*)(src + off);
        ushort4 o;
        o.x = f2bf(v.x); o.y = f2bf(v.y); o.z = f2bf(v.z); o.w = f2bf(v.w);
        *(ushort4*)(wbf + idx) = o;
    } else {
        int i = (bid - 64) * 256 + t;
        int stride = (gridDim.x - 64) * 256;
        for (; i < E; i += stride) atomicAdd(&count[row[i]], 1);
    }
}

// ---------------- 2-phase exclusive scan (block offsets folded into consumers) ----------------
__global__ void k_scan1(const int* __restrict__ in, int total,
                        int* __restrict__ out, int* __restrict__ bsums) {
    __shared__ int sd[256];
    int t = threadIdx.x;
    int base = blockIdx.x * 1024 + t * 4;
    int v0 = (base + 0 < total) ? in[base + 0] : 0;
    int v1 = (base + 1 < total) ? in[base + 1] : 0;
    int v2 = (base + 2 < total) ? in[base + 2] : 0;
    int v3 = (base + 3 < total) ? in[base + 3] : 0;
    int s = v0 + v1 + v2 + v3;
    sd[t] = s; __syncthreads();
    for (int off = 1; off < 256; off <<= 1) {
        int xx = (t >= off) ? sd[t - off] : 0;
        __syncthreads();
        sd[t] += xx;
        __syncthreads();
    }
    int excl = sd[t] - s;
    if (t == 255) bsums[blockIdx.x] = sd[255];
    int run = excl;
    if (base + 0 < total) out[base + 0] = run; run += v0;
    if (base + 1 < total) out[base + 1] = run; run += v1;
    if (base + 2 < total) out[base + 2] = run; run += v2;
    if (base + 3 < total) out[base + 3] = run;
}

__global__ void k_scan2(int* __restrict__ bs, int nb) {
    __shared__ int sd[128];
    int t = threadIdx.x;
    int vv = (t < nb) ? bs[t] : 0;
    sd[t] = vv; __syncthreads();
    for (int off = 1; off < 128; off <<= 1) {
        int xx = (t >= off) ? sd[t - off] : 0;
        __syncthreads();
        sd[t] += xx;
        __syncthreads();
    }
    if (t < nb) bs[t] = sd[t] - vv;   // exclusive
}

// global exclusive prefix of node r = startp[r] + bsums[r >> 10]

// ---------------- FAT kernel: qkv-MFMA blocks first, then edge blocks ----------------
__global__ __launch_bounds__(256) void k_fat(
    const float* __restrict__ x, const unsigned short* __restrict__ wbf,
    const float* __restrict__ qb_, const float* __restrict__ kb_, const float* __restrict__ vb_,
    unsigned short* __restrict__ qkvbf, int n, int qblocks,
    const int* __restrict__ row, const int* __restrict__ col,
    const float* __restrict__ emb, const float* __restrict__ ebw,
    const float* __restrict__ ebb, const int* __restrict__ startp,
    const int* __restrict__ bsums, int* __restrict__ cursor,
    int* __restrict__ col_sorted, unsigned short* __restrict__ bias_s, int E)
{
    __shared__ __align__(16) char sm[17408];
    int bid = blockIdx.x;
    int t = threadIdx.x;

    if (bid < qblocks) {
        unsigned short (*xs)[136] = (unsigned short (*)[136])sm;
        int m0 = bid * 64;
        #pragma unroll
        for (int p = 0; p < 2; ++p) {
            int f = p * 256 + t;
            int r = f >> 3;
            int c16 = (f & 7) * 16;
            int node = m0 + r;
            float4 u0 = {0,0,0,0}, u1 = {0,0,0,0}, u2 = {0,0,0,0}, u3 = {0,0,0,0};
            if (node < n) {
                const float4* px = (const float4*)(x + (size_t)node * HID + c16);
                u0 = px[0]; u1 = px[1]; u2 = px[2]; u3 = px[3];
            }
            union { unsigned short u[8]; short8 v; } a, b;
            a.u[0]=f2bf(u0.x); a.u[1]=f2bf(u0.y); a.u[2]=f2bf(u0.z); a.u[3]=f2bf(u0.w);
            a.u[4]=f2bf(u1.x); a.u[5]=f2bf(u1.y); a.u[6]=f2bf(u1.z); a.u[7]=f2bf(u1.w);
            b.u[0]=f2bf(u2.x); b.u[1]=f2bf(u2.y); b.u[2]=f2bf(u2.z); b.u[3]=f2bf(u2.w);
            b.u[4]=f2bf(u3.x); b.u[5]=f2bf(u3.y); b.u[6]=f2bf(u3.z); b.u[7]=f2bf(u3.w);
            *(short8*)&xs[r][c16]     = a.v;
            *(short8*)&xs[r][c16 + 8] = b.v;
        }
        __syncthreads();

        int w = t >> 6, l = t & 63;
        int lr = l & 15, lc = l >> 4;
        short8 afr[4];
        #pragma unroll
        for (int c = 0; c < 4; ++c)
            afr[c] = *(const short8*)&xs[w * 16 + lr][c * 32 + lc * 8];

        #pragma unroll
        for (int m = 0; m < 3; ++m) {
            const float* bias = (m == 0) ? qb_ : (m == 1) ? kb_ : vb_;
            #pragma unroll
            for (int ct = 0; ct < 8; ++ct) {
                int colg = ct * 16 + lr;
                f32x4 acc = {0.f, 0.f, 0.f, 0.f};
                const unsigned short* wrow = wbf + (size_t)m * 16384 + (size_t)colg * 128 + lc * 8;
                #pragma unroll
                for (int c = 0; c < 4; ++c) {
                    short8 bfr = *(const short8*)(wrow + c * 32);
                    acc = __builtin_amdgcn_mfma_f32_16x16x32_bf16(afr[c], bfr, acc, 0, 0, 0);
                }
                float bv = bias[colg];
                #pragma unroll
                for (int r = 0; r < 4; ++r) {
                    int node = m0 + w * 16 + lc * 4 + r;
                    if (node < n)
                        qkvbf[(size_t)node * 384 + m * 128 + colg] = f2bf(acc[r] + bv);
                }
            }
        }
    } else {
        float (*Wx)[4][8][4] = (float (*)[4][8][4])sm;
        for (int i = t; i < 1024; i += 256) {
            int j = i & 3, g = (i >> 2) & 7, c = (i >> 5) & 3, h = i >> 7;
            Wx[h][c][g][j] = ebw[h * 128 + g * 16 + c * 4 + j];
        }
        float bbr[8];
        #pragma unroll
        for (int i = 0; i < 8; ++i) bbr[i] = ebb[i];
        __syncthreads();

        int l = t & 63;
        int g = l & 7;
        int sub = l >> 3;
        int e = (bid - qblocks) * 32 + (t >> 6) * 8 + sub;
        bool act = e < E;

        float p[8] = {0.f,0.f,0.f,0.f,0.f,0.f,0.f,0.f};
        if (act) {
            const float4* pe = (const float4*)(emb + (size_t)e * HID + g * 16);
            #pragma unroll
            for (int c = 0; c < 4; ++c) {
                float4 ev = pe[c];
                #pragma unroll
                for (int h = 0; h < 8; ++h) {
                    float4 wv = *(const float4*)&Wx[h][c][g][0];
                    p[h] += ev.x*wv.x + ev.y*wv.y + ev.z*wv.z + ev.w*wv.w;
                }
            }
        }
        #pragma unroll
        for (int off = 1; off < 8; off <<= 1) {
            #pragma unroll
            for (int h = 0; h < 8; ++h) p[h] += __shfl_xor(p[h], off);
        }
        if (act && g == 0) {
            int r = row[e];
            int sg = startp[r] + bsums[r >> 10];
            int ps = sg + atomicAdd(&cursor[r], 1);
            col_sorted[ps] = col[e];
            uint4 bv;
            bv.x = pack2bf(p[0] + bbr[0], p[1] + bbr[1]);
            bv.y = pack2bf(p[2] + bbr[2], p[3] + bbr[3]);
            bv.z = pack2bf(p[4] + bbr[4], p[5] + bbr[5]);
            bv.w = pack2bf(p[6] + bbr[6], p[7] + bbr[7]);
            *(uint4*)(bias_s + (size_t)ps * 8) = bv;
        }
    }
}

// ---------------- convert K rows (bf16 in qkv) to OCP fp8 e4m3 via HW pk-convert ----------------
__global__ __launch_bounds__(256) void k_cvtk(
    const unsigned short* __restrict__ qkvbf, unsigned char* __restrict__ kp8, int n)
{
    int i = blockIdx.x * 256 + threadIdx.x;     // one thread = 8 elems
    int node = i >> 4;
    int c8 = (i & 15) * 8;
    if (node >= n) return;
    short8 kv = *(const short8*)(qkvbf + (size_t)node * 384 + 128 + c8);
    float f[8];
    #pragma unroll
    for (int j = 0; j < 8; ++j) f[j] = bf2f((unsigned short)kv[j]);
    unsigned int lo = 0, hi = 0;
    lo = (unsigned int)__builtin_amdgcn_cvt_pk_fp8_f32(f[0], f[1], (int)lo, false);
    lo = (unsigned int)__builtin_amdgcn_cvt_pk_fp8_f32(f[2], f[3], (int)lo, true);
    hi = (unsigned int)__builtin_amdgcn_cvt_pk_fp8_f32(f[4], f[5], (int)hi, false);
    hi = (unsigned int)__builtin_amdgcn_cvt_pk_fp8_f32(f[6], f[7], (int)hi, true);
    uint2 o; o.x = lo; o.y = hi;
    *(uint2*)(kp8 + (size_t)node * HID + c8) = o;
}

// ---------------- L3 pre-warm: sequential read pass over the gather tables ----------------
// Reads allocate in the memory-side L3 (writes do not) — converts attn's random
// gathers from HBM-cold to L3-warm. XOR-guard keeps loads live; the guarded store
// is deterministic and practically never taken.
__global__ __launch_bounds__(256) void k_prewarm(
    const uint4* __restrict__ a, size_t n16, unsigned int* __restrict__ sink)
{
    size_t i = (size_t)blockIdx.x * 256 + threadIdx.x;
    size_t stride = (size_t)gridDim.x * 256;
    unsigned int s = 0;
    for (; i < n16; i += stride) {
        uint4 v = a[i];
        s ^= v.x ^ v.y ^ v.z ^ v.w;
    }
    if (s == 0xDEADBEEFu) sink[blockIdx.x] = s;
}

// ---------------- per-node attention: lane = (edge-slot, head); fp8 K, bf16 V ----------------
__global__ __launch_bounds__(256) void k_attn(
    const unsigned short* __restrict__ qkvbf, const unsigned char* __restrict__ kp8,
    const int* __restrict__ cols, const unsigned short* __restrict__ bias_s,
    const int* __restrict__ startp, const int* __restrict__ bsums,
    unsigned short* __restrict__ aout, int n, int E)
{
    int node = blockIdx.x * 4 + (threadIdx.x >> 6);
    if (node >= n) return;
    int l = threadIdx.x & 63;
    int slot = l >> 3;
    int h = l & 7;
    int s0 = startp[node] + bsums[node >> 10];
    int s1 = startp[node + 1] + bsums[(node + 1) >> 10];
    int deg = s1 - s0;

    float qf[16];
    {
        const unsigned short* qp = qkvbf + (size_t)node * 384 + h * 16;
        short8 q0 = *(const short8*)qp;
        short8 q1 = *(const short8*)(qp + 8);
        #pragma unroll
        for (int i = 0; i < 8; ++i) {
            qf[i] = bf2f((unsigned short)q0[i]);
            qf[8 + i] = bf2f((unsigned short)q1[i]);
        }
    }

    float acc[16];
    #pragma unroll
    for (int i = 0; i < 16; ++i) acc[i] = 0.f;
    float denom = 0.f;

    for (int base = 0; base < deg; base += 8) {
        int idx = base + slot;
        bool act = idx < deg;
        int sidx = s0 + (act ? idx : 0);
        int c = act ? cols[sidx] : 0;
        float eb = act ? bf2f(bias_s[(size_t)sidx * 8 + h]) : 0.f;
        uint4 kw4 = *(const uint4*)(kp8 + (size_t)c * HID + h * 16);
        const unsigned short* vp = qkvbf + (size_t)c * 384 + 256 + h * 16;
        short8 va = *(const short8*)vp;
        short8 vb = *(const short8*)(vp + 8);

        float part = 0.f;
        {
            f32x2 d0 = __builtin_amdgcn_cvt_pk_f32_fp8((int)kw4.x, false);
            f32x2 d1 = __builtin_amdgcn_cvt_pk_f32_fp8((int)kw4.x, true);
            f32x2 d2 = __builtin_amdgcn_cvt_pk_f32_fp8((int)kw4.y, false);
            f32x2 d3 = __builtin_amdgcn_cvt_pk_f32_fp8((int)kw4.y, true);
            f32x2 d4 = __builtin_amdgcn_cvt_pk_f32_fp8((int)kw4.z, false);
            f32x2 d5 = __builtin_amdgcn_cvt_pk_f32_fp8((int)kw4.z, true);
            f32x2 d6 = __builtin_amdgcn_cvt_pk_f32_fp8((int)kw4.w, false);
            f32x2 d7 = __builtin_amdgcn_cvt_pk_f32_fp8((int)kw4.w, true);
            part += qf[0]*d0[0] + qf[1]*d0[1] + qf[2]*d1[0] + qf[3]*d1[1];
            part += qf[4]*d2[0] + qf[5]*d2[1] + qf[6]*d3[0] + qf[7]*d3[1];
            part += qf[8]*d4[0] + qf[9]*d4[1] + qf[10]*d5[0] + qf[11]*d5[1];
            part += qf[12]*d6[0] + qf[13]*d6[1] + qf[14]*d7[0] + qf[15]*d7[1];
        }
        float es = act ? __expf(part * 0.25f + eb) : 0.f;
        denom += es;
        #pragma unroll
        for (int i = 0; i < 8; ++i) acc[i]     += es * bf2f((unsigned short)va[i]);
        #pragma unroll
        for (int i = 0; i < 8; ++i) acc[8 + i] += es * bf2f((unsigned short)vb[i]);
    }

    #pragma unroll
    for (int off = 8; off < 64; off <<= 1) {
        denom += __shfl_xor(denom, off);
        #pragma unroll
        for (int i = 0; i < 16; ++i) acc[i] += __shfl_xor(acc[i], off);
    }
    if (slot == 0) {
        float inv = 1.f / (denom + 1e-10f);
        uint4 o0, o1;
        o0.x = pack2bf(acc[0]*inv,  acc[1]*inv);
        o0.y = pack2bf(acc[2]*inv,  acc[3]*inv);
        o0.z = pack2bf(acc[4]*inv,  acc[5]*inv);
        o0.w = pack2bf(acc[6]*inv,  acc[7]*inv);
        o1.x = pack2bf(acc[8]*inv,  acc[9]*inv);
        o1.y = pack2bf(acc[10]*inv, acc[11]*inv);
        o1.z = pack2bf(acc[12]*inv, acc[13]*inv);
        o1.w = pack2bf(acc[14]*inv, acc[15]*inv);
        unsigned short* op = aout + (size_t)node * HID + h * 16;
        *(uint4*)op       = o0;
        *(uint4*)(op + 8) = o1;
    }
}

// ---------------- final projection via bf16 MFMA: aout(bf16) -> d_out(f32) ----------------
__global__ __launch_bounds__(256) void k_outproj_mfma(
    const unsigned short* __restrict__ aout, const unsigned short* __restrict__ wbf,
    const float* __restrict__ ob, float* __restrict__ out, int n)
{
    __shared__ unsigned short hs[64][136];
    int t = threadIdx.x;
    int m0 = blockIdx.x * 64;
    #pragma unroll
    for (int p = 0; p < 4; ++p) {
        int f = p * 256 + t;
        int r = f >> 4;
        int c8 = (f & 15) * 8;
        int node = m0 + r;
        short8 val = {0,0,0,0,0,0,0,0};
        if (node < n) val = *(const short8*)(aout + (size_t)node * HID + c8);
        *(short8*)&hs[r][c8] = val;
    }
    __syncthreads();

    int w = t >> 6, l = t & 63;
    int lr = l & 15, lc = l >> 4;
    short8 afr[4];
    #pragma unroll
    for (int c = 0; c < 4; ++c)
        afr[c] = *(const short8*)&hs[w * 16 + lr][c * 32 + lc * 8];

    #pragma unroll
    for (int ct = 0; ct < 8; ++ct) {
        int colg = ct * 16 + lr;
        f32x4 acc = {0.f, 0.f, 0.f, 0.f};
        const unsigned short* wrow = wbf + (size_t)3 * 16384 + (size_t)colg * 128 + lc * 8;
        #pragma unroll
        for (int c = 0; c < 4; ++c) {
            short8 bfr = *(const short8*)(wrow + c * 32);
            acc = __builtin_amdgcn_mfma_f32_16x16x32_bf16(afr[c], bfr, acc, 0, 0, 0);
        }
        float bv = ob[colg];
        #pragma unroll
        for (int r = 0; r < 4; ++r) {
            int node = m0 + w * 16 + lc * 4 + r;
            if (node < n)
                out[(size_t)node * HID + colg] = acc[r] + bv;
        }
    }
}

extern "C" void kernel_launch(void* const* d_in, const int* in_sizes, int n_in,
                              void* d_out, int out_size, void* d_ws, size_t ws_size,
                              hipStream_t stream) {
    const float* x   = (const float*)d_in[0];
    const int*   eix = (const int*)  d_in[1];
    const float* emb = (const float*)d_in[2];
    const float* qw  = (const float*)d_in[3];
    const float* qb  = (const float*)d_in[4];
    const float* kw  = (const float*)d_in[5];
    const float* kb  = (const float*)d_in[6];
    const float* vw  = (const float*)d_in[7];
    const float* vb  = (const float*)d_in[8];
    const float* ow  = (const float*)d_in[9];
    const float* ob  = (const float*)d_in[10];
    const float* ebw = (const float*)d_in[11];
    const float* ebb = (const float*)d_in[12];

    int n = in_sizes[0] / HID;
    int E = in_sizes[2] / HID;
    const int* row = eix;
    const int* col = eix + E;

    char* wsp = (char*)d_ws;
    auto alloc = [&](size_t bytes) -> void* {
        void* p = (void*)wsp;
        wsp += (bytes + 255) & ~(size_t)255;
        return p;
    };
    unsigned short* qkvbf = (unsigned short*)alloc((size_t)n * 384 * 2);
    unsigned char* kp8    = (unsigned char*)alloc((size_t)n * HID);
    unsigned short* wbf   = (unsigned short*)alloc((size_t)4 * 16384 * 2);
    int* col_sorted       = (int*)alloc((size_t)E * 4);
    unsigned short* bias_s= (unsigned short*)alloc((size_t)E * 8 * 2);
    unsigned short* aout  = (unsigned short*)alloc((size_t)n * HID * 2);
    char* zbase           = (char*)alloc(0);          // start of zeroed region
    int* count            = (int*)alloc((size_t)(n + 2) * 4);
    int* cursor           = (int*)alloc((size_t)n * 4);
    char* zend            = (char*)alloc(0);          // end of zeroed region
    int* startp           = (int*)alloc((size_t)(n + 2) * 4);
    int* bsums            = (int*)alloc(256 * 4);
    unsigned int* sink    = (unsigned int*)alloc(2048 * 4);

    // one memset covers count + cursor (contiguous in ws)
    hipMemsetAsync(zbase, 0, (size_t)(zend - zbase), stream);

    k_init<<<64 + 2048, 256, 0, stream>>>(qw, kw, vw, ow, wbf, row, E, count);

    int total = n + 1;
    int nb = (total + 1023) / 1024;
    k_scan1<<<nb, 256, 0, stream>>>(count, total, startp, bsums);
    k_scan2<<<1, 128, 0, stream>>>(bsums, nb);

    int qblocks = (n + 63) / 64;
    int eblocks = (E + 31) / 32;
    k_fat<<<qblocks + eblocks, 256, 0, stream>>>(
        x, wbf, qb, kb, vb, qkvbf, n, qblocks,
        row, col, emb, ebw, ebb, startp, bsums, cursor, col_sorted, bias_s, E);

    k_cvtk<<<(n * 16 + 255) / 256, 256, 0, stream>>>(qkvbf, kp8, n);

    // pre-warm L3 over [qkvbf .. kp8 end) — contiguous in ws
    {
        char* beg = (char*)qkvbf;
        char* end = (char*)kp8 + (size_t)n * HID;
        size_t n16 = (size_t)(end - beg) / 16;
        k_prewarm<<<2048, 256, 0, stream>>>((const uint4*)beg, n16, sink);
    }

    k_attn<<<(n + 3) / 4, 256, 0, stream>>>(qkvbf, kp8, col_sorted, bias_s,
                                            startp, bsums, aout, n, E);
    k_outproj_mfma<<<(n + 63) / 64, 256, 0, stream>>>(aout, wbf, ob, (float*)d_out, n);
}

// Round 13
// 551.780 us; speedup vs baseline: 1.0169x; 1.0169x over previous
//
#include <hip/hip_runtime.h>

#define HID 128
#define NH 8

typedef __attribute__((ext_vector_type(8))) short short8;
typedef __attribute__((ext_vector_type(4))) float f32x4;
typedef __attribute__((ext_vector_type(2))) float f32x2;

__device__ __forceinline__ unsigned short f2bf(float f) {
    unsigned int u = __float_as_uint(f);
    u = (u + 0x7FFF + ((u >> 16) & 1)) >> 16;
    return (unsigned short)u;
}
__device__ __forceinline__ float bf2f(unsigned short s) {
    return __uint_as_float((unsigned int)s << 16);
}
__device__ __forceinline__ unsigned int pack2bf(float lo, float hi) {
    return (unsigned int)f2bf(lo) | ((unsigned int)f2bf(hi) << 16);
}

// ---------------- fused: weight conversion (blocks 0..63) + histogram ----------------
__global__ void k_init(const float* __restrict__ qw, const float* __restrict__ kw,
                       const float* __restrict__ vw, const float* __restrict__ ow,
                       unsigned short* __restrict__ wbf,
                       const int* __restrict__ row, int E, int* __restrict__ count) {
    int bid = blockIdx.x;
    int t = threadIdx.x;
    if (bid < 64) {
        int i = bid * 256 + t;
        int idx = i * 4;
        int m = idx >> 14;
        int off = idx & 16383;
        const float* src = (m == 0) ? qw : (m == 1) ? kw : (m == 2) ? vw : ow;
        float4 v = *(const float4*)(src + off);
        ushort4 o;
        o.x = f2bf(v.x); o.y = f2bf(v.y); o.z = f2bf(v.z); o.w = f2bf(v.w);
        *(ushort4*)(wbf + idx) = o;
    } else {
        int i = (bid - 64) * 256 + t;
        int stride = (gridDim.x - 64) * 256;
        for (; i < E; i += stride) atomicAdd(&count[row[i]], 1);
    }
}

// ---------------- 2-phase exclusive scan (block offsets folded into consumers) ----------------
__global__ void k_scan1(const int* __restrict__ in, int total,
                        int* __restrict__ out, int* __restrict__ bsums) {
    __shared__ int sd[256];
    int t = threadIdx.x;
    int base = blockIdx.x * 1024 + t * 4;
    int v0 = (base + 0 < total) ? in[base + 0] : 0;
    int v1 = (base + 1 < total) ? in[base + 1] : 0;
    int v2 = (base + 2 < total) ? in[base + 2] : 0;
    int v3 = (base + 3 < total) ? in[base + 3] : 0;
    int s = v0 + v1 + v2 + v3;
    sd[t] = s; __syncthreads();
    for (int off = 1; off < 256; off <<= 1) {
        int xx = (t >= off) ? sd[t - off] : 0;
        __syncthreads();
        sd[t] += xx;
        __syncthreads();
    }
    int excl = sd[t] - s;
    if (t == 255) bsums[blockIdx.x] = sd[255];
    int run = excl;
    if (base + 0 < total) out[base + 0] = run; run += v0;
    if (base + 1 < total) out[base + 1] = run; run += v1;
    if (base + 2 < total) out[base + 2] = run; run += v2;
    if (base + 3 < total) out[base + 3] = run;
}

__global__ void k_scan2(int* __restrict__ bs, int nb) {
    __shared__ int sd[128];
    int t = threadIdx.x;
    int vv = (t < nb) ? bs[t] : 0;
    sd[t] = vv; __syncthreads();
    for (int off = 1; off < 128; off <<= 1) {
        int xx = (t >= off) ? sd[t - off] : 0;
        __syncthreads();
        sd[t] += xx;
        __syncthreads();
    }
    if (t < nb) bs[t] = sd[t] - vv;   // exclusive
}

// global exclusive prefix of node r = startp[r] + bsums[r >> 10]

// ---------------- FAT kernel: qkv-MFMA blocks first, then edge blocks ----------------
__global__ __launch_bounds__(256) void k_fat(
    const float* __restrict__ x, const unsigned short* __restrict__ wbf,
    const float* __restrict__ qb_, const float* __restrict__ kb_, const float* __restrict__ vb_,
    unsigned short* __restrict__ qkvbf, int n, int qblocks,
    const int* __restrict__ row, const int* __restrict__ col,
    const float* __restrict__ emb, const float* __restrict__ ebw,
    const float* __restrict__ ebb, const int* __restrict__ startp,
    const int* __restrict__ bsums, int* __restrict__ cursor,
    int* __restrict__ col_sorted, unsigned short* __restrict__ bias_s, int E)
{
    __shared__ __align__(16) char sm[17408];
    int bid = blockIdx.x;
    int t = threadIdx.x;

    if (bid < qblocks) {
        unsigned short (*xs)[136] = (unsigned short (*)[136])sm;
        int m0 = bid * 64;
        #pragma unroll
        for (int p = 0; p < 2; ++p) {
            int f = p * 256 + t;
            int r = f >> 3;
            int c16 = (f & 7) * 16;
            int node = m0 + r;
            float4 u0 = {0,0,0,0}, u1 = {0,0,0,0}, u2 = {0,0,0,0}, u3 = {0,0,0,0};
            if (node < n) {
                const float4* px = (const float4*)(x + (size_t)node * HID + c16);
                u0 = px[0]; u1 = px[1]; u2 = px[2]; u3 = px[3];
            }
            union { unsigned short u[8]; short8 v; } a, b;
            a.u[0]=f2bf(u0.x); a.u[1]=f2bf(u0.y); a.u[2]=f2bf(u0.z); a.u[3]=f2bf(u0.w);
            a.u[4]=f2bf(u1.x); a.u[5]=f2bf(u1.y); a.u[6]=f2bf(u1.z); a.u[7]=f2bf(u1.w);
            b.u[0]=f2bf(u2.x); b.u[1]=f2bf(u2.y); b.u[2]=f2bf(u2.z); b.u[3]=f2bf(u2.w);
            b.u[4]=f2bf(u3.x); b.u[5]=f2bf(u3.y); b.u[6]=f2bf(u3.z); b.u[7]=f2bf(u3.w);
            *(short8*)&xs[r][c16]     = a.v;
            *(short8*)&xs[r][c16 + 8] = b.v;
        }
        __syncthreads();

        int w = t >> 6, l = t & 63;
        int lr = l & 15, lc = l >> 4;
        short8 afr[4];
        #pragma unroll
        for (int c = 0; c < 4; ++c)
            afr[c] = *(const short8*)&xs[w * 16 + lr][c * 32 + lc * 8];

        #pragma unroll
        for (int m = 0; m < 3; ++m) {
            const float* bias = (m == 0) ? qb_ : (m == 1) ? kb_ : vb_;
            #pragma unroll
            for (int ct = 0; ct < 8; ++ct) {
                int colg = ct * 16 + lr;
                f32x4 acc = {0.f, 0.f, 0.f, 0.f};
                const unsigned short* wrow = wbf + (size_t)m * 16384 + (size_t)colg * 128 + lc * 8;
                #pragma unroll
                for (int c = 0; c < 4; ++c) {
                    short8 bfr = *(const short8*)(wrow + c * 32);
                    acc = __builtin_amdgcn_mfma_f32_16x16x32_bf16(afr[c], bfr, acc, 0, 0, 0);
                }
                float bv = bias[colg];
                #pragma unroll
                for (int r = 0; r < 4; ++r) {
                    int node = m0 + w * 16 + lc * 4 + r;
                    if (node < n)
                        qkvbf[(size_t)node * 384 + m * 128 + colg] = f2bf(acc[r] + bv);
                }
            }
        }
    } else {
        float (*Wx)[4][8][4] = (float (*)[4][8][4])sm;
        for (int i = t; i < 1024; i += 256) {
            int j = i & 3, g = (i >> 2) & 7, c = (i >> 5) & 3, h = i >> 7;
            Wx[h][c][g][j] = ebw[h * 128 + g * 16 + c * 4 + j];
        }
        float bbr[8];
        #pragma unroll
        for (int i = 0; i < 8; ++i) bbr[i] = ebb[i];
        __syncthreads();

        int l = t & 63;
        int g = l & 7;
        int sub = l >> 3;
        int e = (bid - qblocks) * 32 + (t >> 6) * 8 + sub;
        bool act = e < E;

        float p[8] = {0.f,0.f,0.f,0.f,0.f,0.f,0.f,0.f};
        if (act) {
            const float4* pe = (const float4*)(emb + (size_t)e * HID + g * 16);
            #pragma unroll
            for (int c = 0; c < 4; ++c) {
                float4 ev = pe[c];
                #pragma unroll
                for (int h = 0; h < 8; ++h) {
                    float4 wv = *(const float4*)&Wx[h][c][g][0];
                    p[h] += ev.x*wv.x + ev.y*wv.y + ev.z*wv.z + ev.w*wv.w;
                }
            }
        }
        #pragma unroll
        for (int off = 1; off < 8; off <<= 1) {
            #pragma unroll
            for (int h = 0; h < 8; ++h) p[h] += __shfl_xor(p[h], off);
        }
        if (act && g == 0) {
            int r = row[e];
            int sg = startp[r] + bsums[r >> 10];
            int ps = sg + atomicAdd(&cursor[r], 1);
            col_sorted[ps] = col[e];
            uint4 bv;
            bv.x = pack2bf(p[0] + bbr[0], p[1] + bbr[1]);
            bv.y = pack2bf(p[2] + bbr[2], p[3] + bbr[3]);
            bv.z = pack2bf(p[4] + bbr[4], p[5] + bbr[5]);
            bv.w = pack2bf(p[6] + bbr[6], p[7] + bbr[7]);
            *(uint4*)(bias_s + (size_t)ps * 8) = bv;
        }
    }
}

// ---------------- convert K rows (bf16 in qkv) to OCP fp8 e4m3 via HW pk-convert ----------------
__global__ __launch_bounds__(256) void k_cvtk(
    const unsigned short* __restrict__ qkvbf, unsigned char* __restrict__ kp8, int n)
{
    int i = blockIdx.x * 256 + threadIdx.x;     // one thread = 8 elems
    int node = i >> 4;
    int c8 = (i & 15) * 8;
    if (node >= n) return;
    short8 kv = *(const short8*)(qkvbf + (size_t)node * 384 + 128 + c8);
    float f[8];
    #pragma unroll
    for (int j = 0; j < 8; ++j) f[j] = bf2f((unsigned short)kv[j]);
    unsigned int lo = 0, hi = 0;
    lo = (unsigned int)__builtin_amdgcn_cvt_pk_fp8_f32(f[0], f[1], (int)lo, false);
    lo = (unsigned int)__builtin_amdgcn_cvt_pk_fp8_f32(f[2], f[3], (int)lo, true);
    hi = (unsigned int)__builtin_amdgcn_cvt_pk_fp8_f32(f[4], f[5], (int)hi, false);
    hi = (unsigned int)__builtin_amdgcn_cvt_pk_fp8_f32(f[6], f[7], (int)hi, true);
    uint2 o; o.x = lo; o.y = hi;
    *(uint2*)(kp8 + (size_t)node * HID + c8) = o;
}

// ---------------- per-node attention: lane = (edge-slot, head); fp8 K, bf16 V ----------------
__global__ __launch_bounds__(256) void k_attn(
    const unsigned short* __restrict__ qkvbf, const unsigned char* __restrict__ kp8,
    const int* __restrict__ cols, const unsigned short* __restrict__ bias_s,
    const int* __restrict__ startp, const int* __restrict__ bsums,
    unsigned short* __restrict__ aout, int n, int E)
{
    int node = blockIdx.x * 4 + (threadIdx.x >> 6);
    if (node >= n) return;
    int l = threadIdx.x & 63;
    int slot = l >> 3;
    int h = l & 7;
    int s0 = startp[node] + bsums[node >> 10];
    int s1 = startp[node + 1] + bsums[(node + 1) >> 10];
    int deg = s1 - s0;

    float qf[16];
    {
        const unsigned short* qp = qkvbf + (size_t)node * 384 + h * 16;
        short8 q0 = *(const short8*)qp;
        short8 q1 = *(const short8*)(qp + 8);
        #pragma unroll
        for (int i = 0; i < 8; ++i) {
            qf[i] = bf2f((unsigned short)q0[i]);
            qf[8 + i] = bf2f((unsigned short)q1[i]);
        }
    }

    float acc[16];
    #pragma unroll
    for (int i = 0; i < 16; ++i) acc[i] = 0.f;
    float denom = 0.f;

    for (int base = 0; base < deg; base += 8) {
        int idx = base + slot;
        bool act = idx < deg;
        int sidx = s0 + (act ? idx : 0);
        int c = act ? cols[sidx] : 0;
        float eb = act ? bf2f(bias_s[(size_t)sidx * 8 + h]) : 0.f;
        uint4 kw4 = *(const uint4*)(kp8 + (size_t)c * HID + h * 16);
        const unsigned short* vp = qkvbf + (size_t)c * 384 + 256 + h * 16;
        short8 va = *(const short8*)vp;
        short8 vb = *(const short8*)(vp + 8);

        float part = 0.f;
        {
            f32x2 d0 = __builtin_amdgcn_cvt_pk_f32_fp8((int)kw4.x, false);
            f32x2 d1 = __builtin_amdgcn_cvt_pk_f32_fp8((int)kw4.x, true);
            f32x2 d2 = __builtin_amdgcn_cvt_pk_f32_fp8((int)kw4.y, false);
            f32x2 d3 = __builtin_amdgcn_cvt_pk_f32_fp8((int)kw4.y, true);
            f32x2 d4 = __builtin_amdgcn_cvt_pk_f32_fp8((int)kw4.z, false);
            f32x2 d5 = __builtin_amdgcn_cvt_pk_f32_fp8((int)kw4.z, true);
            f32x2 d6 = __builtin_amdgcn_cvt_pk_f32_fp8((int)kw4.w, false);
            f32x2 d7 = __builtin_amdgcn_cvt_pk_f32_fp8((int)kw4.w, true);
            part += qf[0]*d0[0] + qf[1]*d0[1] + qf[2]*d1[0] + qf[3]*d1[1];
            part += qf[4]*d2[0] + qf[5]*d2[1] + qf[6]*d3[0] + qf[7]*d3[1];
            part += qf[8]*d4[0] + qf[9]*d4[1] + qf[10]*d5[0] + qf[11]*d5[1];
            part += qf[12]*d6[0] + qf[13]*d6[1] + qf[14]*d7[0] + qf[15]*d7[1];
        }
        float es = act ? __expf(part * 0.25f + eb) : 0.f;
        denom += es;
        #pragma unroll
        for (int i = 0; i < 8; ++i) acc[i]     += es * bf2f((unsigned short)va[i]);
        #pragma unroll
        for (int i = 0; i < 8; ++i) acc[8 + i] += es * bf2f((unsigned short)vb[i]);
    }

    #pragma unroll
    for (int off = 8; off < 64; off <<= 1) {
        denom += __shfl_xor(denom, off);
        #pragma unroll
        for (int i = 0; i < 16; ++i) acc[i] += __shfl_xor(acc[i], off);
    }
    if (slot == 0) {
        float inv = 1.f / (denom + 1e-10f);
        uint4 o0, o1;
        o0.x = pack2bf(acc[0]*inv,  acc[1]*inv);
        o0.y = pack2bf(acc[2]*inv,  acc[3]*inv);
        o0.z = pack2bf(acc[4]*inv,  acc[5]*inv);
        o0.w = pack2bf(acc[6]*inv,  acc[7]*inv);
        o1.x = pack2bf(acc[8]*inv,  acc[9]*inv);
        o1.y = pack2bf(acc[10]*inv, acc[11]*inv);
        o1.z = pack2bf(acc[12]*inv, acc[13]*inv);
        o1.w = pack2bf(acc[14]*inv, acc[15]*inv);
        unsigned short* op = aout + (size_t)node * HID + h * 16;
        *(uint4*)op       = o0;
        *(uint4*)(op + 8) = o1;
    }
}

// ---------------- final projection via bf16 MFMA: aout(bf16) -> d_out(f32) ----------------
__global__ __launch_bounds__(256) void k_outproj_mfma(
    const unsigned short* __restrict__ aout, const unsigned short* __restrict__ wbf,
    const float* __restrict__ ob, float* __restrict__ out, int n)
{
    __shared__ unsigned short hs[64][136];
    int t = threadIdx.x;
    int m0 = blockIdx.x * 64;
    #pragma unroll
    for (int p = 0; p < 4; ++p) {
        int f = p * 256 + t;
        int r = f >> 4;
        int c8 = (f & 15) * 8;
        int node = m0 + r;
        short8 val = {0,0,0,0,0,0,0,0};
        if (node < n) val = *(const short8*)(aout + (size_t)node * HID + c8);
        *(short8*)&hs[r][c8] = val;
    }
    __syncthreads();

    int w = t >> 6, l = t & 63;
    int lr = l & 15, lc = l >> 4;
    short8 afr[4];
    #pragma unroll
    for (int c = 0; c < 4; ++c)
        afr[c] = *(const short8*)&hs[w * 16 + lr][c * 32 + lc * 8];

    #pragma unroll
    for (int ct = 0; ct < 8; ++ct) {
        int colg = ct * 16 + lr;
        f32x4 acc = {0.f, 0.f, 0.f, 0.f};
        const unsigned short* wrow = wbf + (size_t)3 * 16384 + (size_t)colg * 128 + lc * 8;
        #pragma unroll
        for (int c = 0; c < 4; ++c) {
            short8 bfr = *(const short8*)(wrow + c * 32);
            acc = __builtin_amdgcn_mfma_f32_16x16x32_bf16(afr[c], bfr, acc, 0, 0, 0);
        }
        float bv = ob[colg];
        #pragma unroll
        for (int r = 0; r < 4; ++r) {
            int node = m0 + w * 16 + lc * 4 + r;
            if (node < n)
                out[(size_t)node * HID + colg] = acc[r] + bv;
        }
    }
}

extern "C" void kernel_launch(void* const* d_in, const int* in_sizes, int n_in,
                              void* d_out, int out_size, void* d_ws, size_t ws_size,
                              hipStream_t stream) {
    const float* x   = (const float*)d_in[0];
    const int*   eix = (const int*)  d_in[1];
    const float* emb = (const float*)d_in[2];
    const float* qw  = (const float*)d_in[3];
    const float* qb  = (const float*)d_in[4];
    const float* kw  = (const float*)d_in[5];
    const float* kb  = (const float*)d_in[6];
    const float* vw  = (const float*)d_in[7];
    const float* vb  = (const float*)d_in[8];
    const float* ow  = (const float*)d_in[9];
    const float* ob  = (const float*)d_in[10];
    const float* ebw = (const float*)d_in[11];
    const float* ebb = (const float*)d_in[12];

    int n = in_sizes[0] / HID;
    int E = in_sizes[2] / HID;
    const int* row = eix;
    const int* col = eix + E;

    char* wsp = (char*)d_ws;
    auto alloc = [&](size_t bytes) -> void* {
        void* p = (void*)wsp;
        wsp += (bytes + 255) & ~(size_t)255;
        return p;
    };
    unsigned short* qkvbf = (unsigned short*)alloc((size_t)n * 384 * 2);
    unsigned char* kp8    = (unsigned char*)alloc((size_t)n * HID);
    unsigned short* wbf   = (unsigned short*)alloc((size_t)4 * 16384 * 2);
    int* col_sorted       = (int*)alloc((size_t)E * 4);
    unsigned short* bias_s= (unsigned short*)alloc((size_t)E * 8 * 2);
    unsigned short* aout  = (unsigned short*)alloc((size_t)n * HID * 2);
    char* zbase           = (char*)alloc(0);          // start of zeroed region
    int* count            = (int*)alloc((size_t)(n + 2) * 4);
    int* cursor           = (int*)alloc((size_t)n * 4);
    char* zend            = (char*)alloc(0);          // end of zeroed region
    int* startp           = (int*)alloc((size_t)(n + 2) * 4);
    int* bsums            = (int*)alloc(256 * 4);

    // one memset covers count + cursor (contiguous in ws)
    hipMemsetAsync(zbase, 0, (size_t)(zend - zbase), stream);

    k_init<<<64 + 2048, 256, 0, stream>>>(qw, kw, vw, ow, wbf, row, E, count);

    int total = n + 1;
    int nb = (total + 1023) / 1024;
    k_scan1<<<nb, 256, 0, stream>>>(count, total, startp, bsums);
    k_scan2<<<1, 128, 0, stream>>>(bsums, nb);

    int qblocks = (n + 63) / 64;
    int eblocks = (E + 31) / 32;
    k_fat<<<qblocks + eblocks, 256, 0, stream>>>(
        x, wbf, qb, kb, vb, qkvbf, n, qblocks,
        row, col, emb, ebw, ebb, startp, bsums, cursor, col_sorted, bias_s, E);

    k_cvtk<<<(n * 16 + 255) / 256, 256, 0, stream>>>(qkvbf, kp8, n);

    k_attn<<<(n + 3) / 4, 256, 0, stream>>>(qkvbf, kp8, col_sorted, bias_s,
                                            startp, bsums, aout, n, E);
    k_outproj_mfma<<<(n + 63) / 64, 256, 0, stream>>>(aout, wbf, ob, (float*)d_out, n);
}